// Round 5
// baseline (1116.644 us; speedup 1.0000x reference)
//
#include <hip/hip_runtime.h>
#include <hip/hip_cooperative_groups.h>
#include <math.h>

namespace cg = cooperative_groups;

// ReDrafterHead: B=64, H=4096, D=512, G3=1536, V=32000, STEPS=4
// Round 5: single persistent cooperative kernel, grid.sync() between phases.
// A-operands pre-split swizzled bf16 hi/lo planes; B split in-kernel; 3-pass
// split-bf16 MFMA; argmax fused in logits epilogue.

typedef __attribute__((ext_vector_type(8))) short short8;
typedef __attribute__((ext_vector_type(4))) float f32x4;

__device__ __forceinline__ unsigned short f2bf_rne(float x) {
    unsigned u = __float_as_uint(x);
    unsigned r = (u + 0x7fffu + ((u >> 16) & 1u)) >> 16;
    return (unsigned short)r;
}
__device__ __forceinline__ void split2(float x, unsigned short& hi, unsigned short& lo) {
    unsigned u = __float_as_uint(x);
    hi = (unsigned short)(u >> 16);
    float r = x - __uint_as_float(u & 0xffff0000u);
    lo = f2bf_rne(r);
}

// swizzled plane store: row stride 512 elems (1024 B)
__device__ __forceinline__ void store_plane(unsigned short* hiP, unsigned short* loP,
                                            int m, int d, float v) {
    int s = d >> 6, cl = (d >> 3) & 7, e = d & 7;
    int off = m * 512 + s * 64 + ((cl ^ (m & 7)) * 8) + e;
    unsigned short hi, lo; split2(v, hi, lo);
    hiP[off] = hi; loP[off] = lo;
}

__device__ __forceinline__ void gload16(const void* g, void* lds) {
    __builtin_amdgcn_global_load_lds(
        (const __attribute__((address_space(1))) unsigned int*)g,
        (__attribute__((address_space(3))) unsigned int*)lds, 16, 0, 0);
}

#define LDTB 72   // B LDS row stride (ushorts)

// ---------------------------------------------------------------------------
// MFMA GEMM, 512 threads (8 waves). C[0..63][n0..n0+127] over k [k0,k0+klen).
// A: pre-split swizzled bf16 planes (row stride AstrideB bytes).
// W: fp32 [N][ldbK], split in-kernel. Wave wv owns cols [wv*16,(wv+1)*16).
// ---------------------------------------------------------------------------
template<bool ARGMAX>
__device__ __forceinline__ void mfma_gemm(
    const char* __restrict__ AH, const char* __restrict__ AL, int AstrideB,
    const float* __restrict__ W, int ldbK,
    int n0, int k0, int klen,
    float* __restrict__ C, int ldc,
    unsigned short* AsH, unsigned short* AsL,
    unsigned short* BsH, unsigned short* BsL,
    float* __restrict__ pval, int* __restrict__ pidx, int bx)
{
    const int tid  = threadIdx.x;
    const int wv   = tid >> 6;
    const int lane = tid & 63;
    const int lr   = lane & 15;
    const int lh   = lane >> 4;

    f32x4 acc[4];
#pragma unroll
    for (int i = 0; i < 4; ++i) acc[i] = (f32x4){0.f, 0.f, 0.f, 0.f};

    for (int kk = k0; kk < k0 + klen; kk += 64) {
        {   // A tiles: identity copy of swizzled planes
            int m  = tid >> 3;
            int cp = tid & 7;
            const char* sH = AH + m * AstrideB + kk * 2 + cp * 16;
            const char* sL = AL + m * AstrideB + kk * 2 + cp * 16;
            gload16(sH, (char*)AsH + wv * 1024);
            gload16(sL, (char*)AsL + wv * 1024);
        }
        // B tile: fp32 load + split
#pragma unroll
        for (int r = 0; r < 4; ++r) {
            int idx = r * 512 + tid;      // 2048 float4 slots
            int n = idx >> 4;
            int q = idx & 15;
            float4 v = *(const float4*)(W + (n0 + n) * ldbK + kk + q * 4);
            unsigned short h0,h1,h2,h3,l0,l1,l2,l3;
            split2(v.x,h0,l0); split2(v.y,h1,l1); split2(v.z,h2,l2); split2(v.w,h3,l3);
            uint2 ph = make_uint2((unsigned)h0 | ((unsigned)h1 << 16),
                                  (unsigned)h2 | ((unsigned)h3 << 16));
            uint2 pl = make_uint2((unsigned)l0 | ((unsigned)l1 << 16),
                                  (unsigned)l2 | ((unsigned)l3 << 16));
            *(uint2*)(BsH + n * LDTB + q * 4) = ph;
            *(uint2*)(BsL + n * LDTB + q * 4) = pl;
        }
        __syncthreads();

#pragma unroll
        for (int kk2 = 0; kk2 < 2; ++kk2) {
            int aoff = lr * 64 + (((kk2 * 4 + lh) ^ (lr & 7)) * 8);
            short8 ah[4], al[4];
#pragma unroll
            for (int mt = 0; mt < 4; ++mt) {
                ah[mt] = *(const short8*)(AsH + mt * 1024 + aoff);
                al[mt] = *(const short8*)(AsL + mt * 1024 + aoff);
            }
            int boff = (wv * 16 + lr) * LDTB + kk2 * 32 + lh * 8;
            short8 bh = *(const short8*)(BsH + boff);
            short8 bl = *(const short8*)(BsL + boff);
#pragma unroll
            for (int mt = 0; mt < 4; ++mt) {
                acc[mt] = __builtin_amdgcn_mfma_f32_16x16x32_bf16(ah[mt], bh, acc[mt], 0, 0, 0);
                acc[mt] = __builtin_amdgcn_mfma_f32_16x16x32_bf16(ah[mt], bl, acc[mt], 0, 0, 0);
                acc[mt] = __builtin_amdgcn_mfma_f32_16x16x32_bf16(al[mt], bh, acc[mt], 0, 0, 0);
            }
        }
        __syncthreads();
    }

#pragma unroll
    for (int mt = 0; mt < 4; ++mt)
#pragma unroll
        for (int i = 0; i < 4; ++i) {
            int m = mt * 16 + lh * 4 + i;
            C[m * ldc + n0 + wv * 16 + lr] = acc[mt][i];
        }

    if (ARGMAX) {
        float* sv = (float*)AsH;
        int*   sc = (int*)AsL;
#pragma unroll
        for (int mt = 0; mt < 4; ++mt)
#pragma unroll
            for (int i = 0; i < 4; ++i) {
                float v = acc[mt][i];
                int   c = n0 + wv * 16 + lr;
#pragma unroll
                for (int msk = 1; msk < 16; msk <<= 1) {
                    float ov = __shfl_xor(v, msk, 64);
                    int   oc = __shfl_xor(c, msk, 64);
                    if (ov > v || (ov == v && oc < c)) { v = ov; c = oc; }
                }
                if (lr == 0) {
                    int row = mt * 16 + lh * 4 + i;
                    sv[wv * 64 + row] = v;
                    sc[wv * 64 + row] = c;
                }
            }
        __syncthreads();
        if (tid < 64) {
            float v = sv[tid]; int c = sc[tid];
#pragma unroll
            for (int w = 1; w < 8; ++w) {
                float ov = sv[w * 64 + tid]; int oc = sc[w * 64 + tid];
                if (ov > v) { v = ov; c = oc; }   // ascending cols -> first occurrence
            }
            pval[bx * 64 + tid] = v;
            pidx[bx * 64 + tid] = c;
        }
        __syncthreads();
    }
}

struct Params {
    const float *hidden, *in_w, *in_b;
    const float *w_ih0, *w_hh0, *b_ih0, *b_hh0;
    const float *w_ih1, *w_hh1, *b_ih1, *b_hh1;
    const float *embed, *out_w;
    float* out;
    char *hidH, *hidL;
    float* ipart;
    float *hA, *hB;
    unsigned short *xH, *xL, *hAH, *hAL, *hBH, *hBL;
    float *gip, *ghp;
    float* pval; int* pidx;
};

__device__ __forceinline__ void combine_elem(
    int i, const float* gip, const float* ghp,
    const float* b_ih, const float* b_hh,
    float* h, unsigned short* hH, unsigned short* hL)
{
    int b = i >> 9;
    int d = i & 511;
    int base = b * 1536 + d;
    float ir = b_ih[d], iz = b_ih[d + 512], inn = b_ih[d + 1024];
    float hr = b_hh[d], hz = b_hh[d + 512], hn = b_hh[d + 1024];
#pragma unroll
    for (int s = 0; s < 4; ++s) {
        const float* g = gip + s * 98304 + base;
        const float* q = ghp + s * 98304 + base;
        ir += g[0]; iz += g[512]; inn += g[1024];
        hr += q[0]; hz += q[512]; hn += q[1024];
    }
    float r = 1.f / (1.f + expf(-(ir + hr)));
    float z = 1.f / (1.f + expf(-(iz + hz)));
    float n = tanhf(inn + r * hn);
    float hv = (1.f - z) * n + z * h[i];
    h[i] = hv;
    store_plane(hH, hL, b, d, hv);
}

// gates task t in [0,96): mat=t/48, ks=(t/12)&3, nt=t%12; k-chunk 128
__device__ __forceinline__ void gates_task(
    int t,
    const unsigned short* xH, const unsigned short* xL,
    const unsigned short* hH, const unsigned short* hL,
    const float* w_ih, const float* w_hh,
    float* gip, float* ghp,
    unsigned short* AsH, unsigned short* AsL,
    unsigned short* BsH, unsigned short* BsL)
{
    int mat = t / 48;
    int ks  = (t / 12) & 3;
    int nt  = t % 12;
    const char* AH = (const char*)(mat ? hH : xH);
    const char* AL = (const char*)(mat ? hL : xL);
    const float* W = mat ? w_hh : w_ih;
    float* C = (mat ? ghp : gip) + ks * 98304;
    mfma_gemm<false>(AH, AL, 1024, W, 512, nt * 128, ks * 128, 128, C, 1536,
                     AsH, AsL, BsH, BsL, nullptr, nullptr, 0);
}

__global__ __launch_bounds__(512, 2) void k_persist(Params p)
{
    __shared__ alignas(16) unsigned short AsH[64 * 64];
    __shared__ alignas(16) unsigned short AsL[64 * 64];
    __shared__ alignas(16) unsigned short BsH[128 * LDTB];
    __shared__ alignas(16) unsigned short BsL[128 * LDTB];

    cg::grid_group grid = cg::this_grid();
    const int bx  = blockIdx.x;
    const int tid = threadIdx.x;
    const int gtid = bx * 512 + tid;

    // ---- P0: split hidden[64,4096] -> swizzled planes (stride 8192 B) ----
    if (gtid < 32768) {
        int m = gtid >> 9;
        int cc = gtid & 511;
        int s = cc >> 3, cl = cc & 7;
        const float* src = p.hidden + m * 4096 + cc * 8;
        float4 v0 = *(const float4*)src;
        float4 v1 = *(const float4*)(src + 4);
        unsigned short h[8], l[8];
        split2(v0.x,h[0],l[0]); split2(v0.y,h[1],l[1]); split2(v0.z,h[2],l[2]); split2(v0.w,h[3],l[3]);
        split2(v1.x,h[4],l[4]); split2(v1.y,h[5],l[5]); split2(v1.z,h[6],l[6]); split2(v1.w,h[7],l[7]);
        uint4 ph = make_uint4((unsigned)h[0]|((unsigned)h[1]<<16), (unsigned)h[2]|((unsigned)h[3]<<16),
                              (unsigned)h[4]|((unsigned)h[5]<<16), (unsigned)h[6]|((unsigned)h[7]<<16));
        uint4 pl = make_uint4((unsigned)l[0]|((unsigned)l[1]<<16), (unsigned)l[2]|((unsigned)l[3]<<16),
                              (unsigned)l[4]|((unsigned)l[5]<<16), (unsigned)l[6]|((unsigned)l[7]<<16));
        int off = m * 8192 + s * 128 + ((cl ^ (m & 7)) * 16);
        *(uint4*)(p.hidH + off) = ph;
        *(uint4*)(p.hidL + off) = pl;
    }
    grid.sync();

    // ---- P1: in_proj, 32 blocks (4 nt x 8 ks) ----
    if (bx < 32) {
        int nt = bx & 3, ks = bx >> 2;
        mfma_gemm<false>(p.hidH, p.hidL, 8192, p.in_w, 4096, nt * 128, ks * 512, 512,
                         p.ipart + ks * 32768, 512, AsH, AsL, BsH, BsL, nullptr, nullptr, 0);
    }
    grid.sync();

    // ---- P2: reduce in_proj + bias -> hA,hB (+planes), x=0 planes ----
    if (gtid < 32768) {
        int b = gtid >> 9, d = gtid & 511;
        float s = p.in_b[d];
#pragma unroll
        for (int ks = 0; ks < 8; ++ks) s += p.ipart[ks * 32768 + gtid];
        p.hA[gtid] = s;
        p.hB[gtid] = s;
        store_plane(p.hAH, p.hAL, b, d, s);
        store_plane(p.hBH, p.hBL, b, d, s);
        store_plane(p.xH,  p.xL,  b, d, 0.f);
    }
    grid.sync();

    for (int step = 0; step < 4; ++step) {
        // ---- gates L0 ----
        if (bx < 96)
            gates_task(bx, p.xH, p.xL, p.hAH, p.hAL, p.w_ih0, p.w_hh0,
                       p.gip, p.ghp, AsH, AsL, BsH, BsL);
        grid.sync();
        // ---- combine L0 -> hA ----
        if (gtid < 32768)
            combine_elem(gtid, p.gip, p.ghp, p.b_ih0, p.b_hh0, p.hA, p.hAH, p.hAL);
        grid.sync();
        // ---- gates L1 ----
        if (bx < 96)
            gates_task(bx, p.hAH, p.hAL, p.hBH, p.hBL, p.w_ih1, p.w_hh1,
                       p.gip, p.ghp, AsH, AsL, BsH, BsL);
        grid.sync();
        // ---- combine L1 -> hB ----
        if (gtid < 32768)
            combine_elem(gtid, p.gip, p.ghp, p.b_ih1, p.b_hh1, p.hB, p.hBH, p.hBL);
        grid.sync();
        // ---- logits + argmax partials ----
        if (bx < 250)
            mfma_gemm<true>((const char*)p.hBH, (const char*)p.hBL, 1024,
                            p.out_w, 512, bx * 128, 0, 512,
                            p.out + step * 32000, 128000,
                            AsH, AsL, BsH, BsL, p.pval, p.pidx, bx);
        grid.sync();
        // ---- argmax reduce (first-occurrence) + embed gather -> x planes ----
        if (bx < 64) {
            float* sv = (float*)AsH;
            int*   sc = (int*)AsL;
            if (tid < 256) {
                float v = -3.4e38f; int c = 0x7fffffff;
                if (tid < 250) { v = p.pval[tid * 64 + bx]; c = p.pidx[tid * 64 + bx]; }
                sv[tid] = v; sc[tid] = c;
            }
            __syncthreads();
            for (int s = 128; s > 0; s >>= 1) {
                if (tid < s) {
                    float ov = sv[tid + s]; int oc = sc[tid + s];
                    if (ov > sv[tid] || (ov == sv[tid] && oc < sc[tid])) { sv[tid] = ov; sc[tid] = oc; }
                }
                __syncthreads();
            }
            int tok = sc[0];
            store_plane(p.xH, p.xL, bx, tid, p.embed[tok * 512 + tid]);
        }
        grid.sync();
    }
}

// ---------------------------------------------------------------------------
extern "C" void kernel_launch(void* const* d_in, const int* in_sizes, int n_in,
                              void* d_out, int out_size, void* d_ws, size_t ws_size,
                              hipStream_t stream)
{
    char* ws = (char*)d_ws;
    Params p;
    p.hidden = (const float*)d_in[0];
    p.in_w   = (const float*)d_in[1];
    p.in_b   = (const float*)d_in[2];
    p.w_ih0  = (const float*)d_in[3];
    p.w_hh0  = (const float*)d_in[4];
    p.b_ih0  = (const float*)d_in[5];
    p.b_hh0  = (const float*)d_in[6];
    p.w_ih1  = (const float*)d_in[7];
    p.w_hh1  = (const float*)d_in[8];
    p.b_ih1  = (const float*)d_in[9];
    p.b_hh1  = (const float*)d_in[10];
    p.embed  = (const float*)d_in[11];
    p.out_w  = (const float*)d_in[12];
    p.out    = (float*)d_out;

    p.hidH = ws + 0;
    p.hidL = ws + 524288;
    p.ipart= (float*)(ws + 1048576);
    p.hA   = (float*)(ws + 2097152);
    p.hB   = (float*)(ws + 2228224);
    p.xH   = (unsigned short*)(ws + 2359296);
    p.xL   = (unsigned short*)(ws + 2424832);
    p.hAH  = (unsigned short*)(ws + 2490368);
    p.hAL  = (unsigned short*)(ws + 2555904);
    p.hBH  = (unsigned short*)(ws + 2621440);
    p.hBL  = (unsigned short*)(ws + 2686976);
    p.gip  = (float*)(ws + 2752512);
    p.ghp  = (float*)(ws + 4325376);
    p.pval = (float*)(ws + 5898240);
    p.pidx = (int*)  (ws + 5962240);

    void* kp[] = { (void*)&p };
    hipLaunchCooperativeKernel((const void*)k_persist, dim3(256), dim3(512),
                               kp, 0, stream);
}